// Round 1
// baseline (980.358 us; speedup 1.0000x reference)
//
#include <hip/hip_runtime.h>

typedef float f32x4 __attribute__((ext_vector_type(4)));
typedef float f32x2 __attribute__((ext_vector_type(2)));
typedef short bf16x8 __attribute__((ext_vector_type(8)));
typedef unsigned int u32;
typedef unsigned short u16;

#define DEVI static __device__ __forceinline__

static constexpr int MROWS = 320000;   // N*K rows
static constexpr int HD    = 256;      // hidden
static constexpr int NNODE = 10000;

DEVI u16 f2bf(float f) {
  u32 u = __builtin_bit_cast(u32, f);
  u = (u + 0x7fffu + ((u >> 16) & 1u)) >> 16;   // RNE
  return (u16)u;
}
DEVI float bf2f(u16 s) {
  u32 u = ((u32)s) << 16;
  return __builtin_bit_cast(float, u);
}
DEVI float gelu_f(float y) {
  // tanh-approx gelu: y * E/(E+1), E = exp(2*0.79788456*(y+0.044715 y^3))
  float z = 0.7978845608028654f * (y + 0.044715f * y * y * y);
  float E = __expf(2.f * z);
  return y * (1.f - 1.f / (E + 1.f));
}

// ---------------- weight prep ----------------
// Wlt [256][128] = W_lin^T (bf16); W1gt[256][256] = (g_pre*W_ff1)^T; W2t = W_ff2^T
__global__ void prep_weights(const float* __restrict__ W_lin, const float* __restrict__ g_pre,
                             const float* __restrict__ W_ff1, const float* __restrict__ W_ff2,
                             u16* __restrict__ Wlt, u16* __restrict__ W1gt, u16* __restrict__ W2t)
{
  int e = blockIdx.x * 256 + threadIdx.x;
  if (e < 32768) {
    int c = e >> 7, k = e & 127;
    Wlt[e] = f2bf(W_lin[k * 256 + c]);
  } else if (e < 32768 + 65536) {
    int e2 = e - 32768; int c = e2 >> 8, k = e2 & 255;
    W1gt[e2] = f2bf(g_pre[k] * W_ff1[k * 256 + c]);
  } else if (e < 163840) {
    int e3 = e - 98304; int c = e3 >> 8, k = e3 & 255;
    W2t[e3] = f2bf(W_ff2[k * 256 + c]);
  }
}

// u[c] = sum_k g_pre[k]*W_ff1[k][c];  v[c] = sum_k b_pre[k]*W_ff1[k][c] + b_ff1[c]
__global__ void prep_uv(const float* __restrict__ W_ff1, const float* __restrict__ g_pre,
                        const float* __restrict__ b_pre, const float* __restrict__ b_ff1,
                        float* __restrict__ u, float* __restrict__ v)
{
  int c = threadIdx.x;
  float uu = 0.f, vv = 0.f;
  for (int k = 0; k < 256; ++k) {
    float w = W_ff1[k * 256 + c];
    uu += g_pre[k] * w;
    vv += b_pre[k] * w;
  }
  u[c] = uu;
  v[c] = vv + b_ff1[c];
}

// ---------------- fused GEMM template ----------------
// C^T register layout: mfma(W_frag, A_frag, acc) -> lane holds row = tile0+rg*16+(lane&15),
// cols = colbase + nt*16 + (lane>>4)*4 + {0..3}.
// EPI 0: K1  A=fp32 edge_features [M][128]; p0=b_lin; writes eh bf16 + stats(m,rs)
// EPI 1: K2  A=eh bf16 [M][256]; p0=u, p1=v, p2=stats; writes g bf16 (folded LN + gelu)
// EPI 2: K3  A=g bf16; p0=b_ff2, p1=g_edge, p2=b_edge; eh_resid=eh; writes edge_out fp32 + eo bf16 (in-place over g)
template<int KD, int EPI>
__global__ __launch_bounds__(256, 2)
void gemm_k(const void* Aptr, const u16* __restrict__ Wt,
            const float* __restrict__ p0, const float* __restrict__ p1,
            const float* __restrict__ p2,
            float* __restrict__ stats_out,
            u16* out_b, const u16* __restrict__ eh_resid,
            float* __restrict__ out_f)
{
  const int tid  = threadIdx.x;
  const int wid  = tid >> 6;
  const int lane = tid & 63;
  const int lo   = lane & 15;
  const int hi   = lane >> 4;
  const int tile0   = blockIdx.x * 128;
  const int colbase = wid * 64;

  __shared__ char  lds[32768];          // W quarter [256 rows][64 k] bf16, XOR-swizzled
  __shared__ float part[4][128][2];
  __shared__ float rowstats[128][2];

  f32x4 acc[8][4];
#pragma unroll
  for (int rg = 0; rg < 8; ++rg)
#pragma unroll
    for (int nt = 0; nt < 4; ++nt) acc[rg][nt] = f32x4{0.f, 0.f, 0.f, 0.f};

  constexpr int NQ = KD / 64;
#pragma unroll 1
  for (int q = 0; q < NQ; ++q) {
    __syncthreads();
#pragma unroll
    for (int i = 0; i < 8; ++i) {                    // stage 32KB quarter
      int chunk = tid + i * 256;                     // 2048 chunks of 8 bf16
      int c  = chunk >> 3;
      int kk = chunk & 7;
      const char* gsrc = (const char*)Wt + (size_t)c * (KD * 2) + q * 128 + kk * 16;
      int loff = (c * 128 + kk * 16) ^ ((c & 7) << 4);
      *(bf16x8*)(lds + loff) = *(const bf16x8*)gsrc;
    }
    __syncthreads();
#pragma unroll
    for (int s = 0; s < 2; ++s) {
      const int ks = q * 2 + s;                      // global 32-wide K step
      bf16x8 a[8];
      if constexpr (EPI == 0) {
        const float* A = (const float*)Aptr;
#pragma unroll
        for (int rg = 0; rg < 8; ++rg) {
          int r = tile0 + rg * 16 + lo;
          const float* psrc = A + (size_t)r * KD + ks * 32 + hi * 8;
          f32x4 x0 = *(const f32x4*)psrc;
          f32x4 x1 = *(const f32x4*)(psrc + 4);
          bf16x8 t;
          t[0] = (short)f2bf(x0[0]); t[1] = (short)f2bf(x0[1]);
          t[2] = (short)f2bf(x0[2]); t[3] = (short)f2bf(x0[3]);
          t[4] = (short)f2bf(x1[0]); t[5] = (short)f2bf(x1[1]);
          t[6] = (short)f2bf(x1[2]); t[7] = (short)f2bf(x1[3]);
          a[rg] = t;
        }
      } else {
        const u16* A = (const u16*)Aptr;
#pragma unroll
        for (int rg = 0; rg < 8; ++rg) {
          int r = tile0 + rg * 16 + lo;
          a[rg] = *(const bf16x8*)(A + (size_t)r * KD + ks * 32 + hi * 8);
        }
      }
      bf16x8 b[4];
#pragma unroll
      for (int nt = 0; nt < 4; ++nt) {
        int c = colbase + nt * 16 + lo;
        int loff = (c * 128 + s * 64 + hi * 16) ^ ((c & 7) << 4);
        b[nt] = *(const bf16x8*)(lds + loff);
      }
#pragma unroll
      for (int nt = 0; nt < 4; ++nt)
#pragma unroll
        for (int rg = 0; rg < 8; ++rg)
          acc[rg][nt] = __builtin_amdgcn_mfma_f32_16x16x32_bf16(b[nt], a[rg], acc[rg][nt], 0, 0, 0);
    }
  }

  if constexpr (EPI == 0) {
    f32x4 bl[4];
#pragma unroll
    for (int nt = 0; nt < 4; ++nt)
      bl[nt] = *(const f32x4*)(p0 + colbase + nt * 16 + hi * 4);
#pragma unroll
    for (int rg = 0; rg < 8; ++rg) {
      int r = tile0 + rg * 16 + lo;
      float ss = 0.f, qq = 0.f;
#pragma unroll
      for (int nt = 0; nt < 4; ++nt) {
        f32x4 x = acc[rg][nt] + bl[nt];
        u32 w0 = (u32)f2bf(x[0]) | ((u32)f2bf(x[1]) << 16);
        u32 w1 = (u32)f2bf(x[2]) | ((u32)f2bf(x[3]) << 16);
        u32* dst = (u32*)(out_b + (size_t)r * HD + colbase + nt * 16 + hi * 4);
        dst[0] = w0; dst[1] = w1;
        ss += x[0] + x[1] + x[2] + x[3];
        qq += x[0]*x[0] + x[1]*x[1] + x[2]*x[2] + x[3]*x[3];
      }
      ss += __shfl_xor(ss, 16); ss += __shfl_xor(ss, 32);
      qq += __shfl_xor(qq, 16); qq += __shfl_xor(qq, 32);
      if (hi == 0) { part[wid][rg * 16 + lo][0] = ss; part[wid][rg * 16 + lo][1] = qq; }
    }
    __syncthreads();
    if (tid < 128) {
      float ss = part[0][tid][0] + part[1][tid][0] + part[2][tid][0] + part[3][tid][0];
      float qq = part[0][tid][1] + part[1][tid][1] + part[2][tid][1] + part[3][tid][1];
      float m  = ss * (1.f / 256.f);
      float var = qq * (1.f / 256.f) - m * m;
      float rs = rsqrtf(var + 1e-5f);
      stats_out[(size_t)(tile0 + tid) * 2]     = m;
      stats_out[(size_t)(tile0 + tid) * 2 + 1] = rs;
    }
  }

  if constexpr (EPI == 1) {
    f32x4 u4[4], v4[4];
#pragma unroll
    for (int nt = 0; nt < 4; ++nt) {
      u4[nt] = *(const f32x4*)(p0 + colbase + nt * 16 + hi * 4);
      v4[nt] = *(const f32x4*)(p1 + colbase + nt * 16 + hi * 4);
    }
#pragma unroll
    for (int rg = 0; rg < 8; ++rg) {
      int r = tile0 + rg * 16 + lo;
      f32x2 mr = *(const f32x2*)(p2 + (size_t)r * 2);
      float rs = mr[1], rm = mr[0] * mr[1];
#pragma unroll
      for (int nt = 0; nt < 4; ++nt) {
        f32x4 y = acc[rg][nt] * rs - u4[nt] * rm + v4[nt];
        u32 w0 = (u32)f2bf(gelu_f(y[0])) | ((u32)f2bf(gelu_f(y[1])) << 16);
        u32 w1 = (u32)f2bf(gelu_f(y[2])) | ((u32)f2bf(gelu_f(y[3])) << 16);
        u32* dst = (u32*)(out_b + (size_t)r * HD + colbase + nt * 16 + hi * 4);
        dst[0] = w0; dst[1] = w1;
      }
    }
  }

  if constexpr (EPI == 2) {
    f32x4 b2[4], ge[4], be[4];
#pragma unroll
    for (int nt = 0; nt < 4; ++nt) {
      b2[nt] = *(const f32x4*)(p0 + colbase + nt * 16 + hi * 4);
      ge[nt] = *(const f32x4*)(p1 + colbase + nt * 16 + hi * 4);
      be[nt] = *(const f32x4*)(p2 + colbase + nt * 16 + hi * 4);
    }
    f32x4 eo[8][4];
#pragma unroll
    for (int rg = 0; rg < 8; ++rg) {
      int r = tile0 + rg * 16 + lo;
      float ss = 0.f, qq = 0.f;
#pragma unroll
      for (int nt = 0; nt < 4; ++nt) {
        const u16* ep = eh_resid + (size_t)r * HD + colbase + nt * 16 + hi * 4;
        u32 e0 = *(const u32*)ep;
        u32 e1 = *(const u32*)(ep + 2);
        f32x4 x = acc[rg][nt] + b2[nt];
        x[0] += bf2f((u16)(e0 & 0xffffu));
        x[1] += bf2f((u16)(e0 >> 16));
        x[2] += bf2f((u16)(e1 & 0xffffu));
        x[3] += bf2f((u16)(e1 >> 16));
        eo[rg][nt] = x;
        ss += x[0] + x[1] + x[2] + x[3];
        qq += x[0]*x[0] + x[1]*x[1] + x[2]*x[2] + x[3]*x[3];
      }
      ss += __shfl_xor(ss, 16); ss += __shfl_xor(ss, 32);
      qq += __shfl_xor(qq, 16); qq += __shfl_xor(qq, 32);
      if (hi == 0) { part[wid][rg * 16 + lo][0] = ss; part[wid][rg * 16 + lo][1] = qq; }
    }
    __syncthreads();
    if (tid < 128) {
      float ss = part[0][tid][0] + part[1][tid][0] + part[2][tid][0] + part[3][tid][0];
      float qq = part[0][tid][1] + part[1][tid][1] + part[2][tid][1] + part[3][tid][1];
      float m  = ss * (1.f / 256.f);
      float var = qq * (1.f / 256.f) - m * m;
      rowstats[tid][0] = m;
      rowstats[tid][1] = rsqrtf(var + 1e-5f);
    }
    __syncthreads();
#pragma unroll
    for (int rg = 0; rg < 8; ++rg) {
      int rl = rg * 16 + lo;
      int r  = tile0 + rl;
      float m = rowstats[rl][0], rs = rowstats[rl][1];
#pragma unroll
      for (int nt = 0; nt < 4; ++nt) {
        f32x4 x = eo[rg][nt];
        u32 w0 = (u32)f2bf(x[0]) | ((u32)f2bf(x[1]) << 16);
        u32 w1 = (u32)f2bf(x[2]) | ((u32)f2bf(x[3]) << 16);
        u32* db = (u32*)(out_b + (size_t)r * HD + colbase + nt * 16 + hi * 4);
        db[0] = w0; db[1] = w1;
        f32x4 o = (x - m) * rs * ge[nt] + be[nt];
        *(f32x4*)(out_f + (size_t)r * HD + colbase + nt * 16 + hi * 4) = o;
      }
    }
  }
}

// ---------------- node aggregation + node LN ----------------
__global__ __launch_bounds__(256)
void node_kernel(const u16* __restrict__ eo, const int* __restrict__ mask,
                 const float* __restrict__ g_node, const float* __restrict__ b_node,
                 float* __restrict__ out)
{
  int n   = blockIdx.x;
  int tid = threadIdx.x;
  __shared__ int   lm[32];
  __shared__ float plds[8][256];
  __shared__ float red[2][4];
  if (tid < 32) lm[tid] = mask[n * 32 + tid];
  __syncthreads();
  int chunk = tid & 31;    // 8-col chunk
  int g0    = tid >> 5;    // row group 0..7
  float p[8] = {0.f, 0.f, 0.f, 0.f, 0.f, 0.f, 0.f, 0.f};
#pragma unroll
  for (int i = 0; i < 4; ++i) {
    int row = g0 + i * 8;
    if (lm[row] != 0) {
      const u16* src = eo + ((size_t)n * 32 + row) * HD + chunk * 8;
      bf16x8 v = *(const bf16x8*)src;
#pragma unroll
      for (int j = 0; j < 8; ++j) p[j] += bf2f((u16)v[j]);
    }
  }
#pragma unroll
  for (int j = 0; j < 8; ++j) plds[g0][chunk * 8 + j] = p[j];
  __syncthreads();
  int col = tid;
  float s = 0.f;
#pragma unroll
  for (int g = 0; g < 8; ++g) s += plds[g][col];
  float ss = s, qq = s * s;
#pragma unroll
  for (int d = 1; d < 64; d <<= 1) { ss += __shfl_xor(ss, d); qq += __shfl_xor(qq, d); }
  if ((tid & 63) == 0) { red[0][tid >> 6] = ss; red[1][tid >> 6] = qq; }
  __syncthreads();
  ss = red[0][0] + red[0][1] + red[0][2] + red[0][3];
  qq = red[1][0] + red[1][1] + red[1][2] + red[1][3];
  float m  = ss * (1.f / 256.f);
  float var = qq * (1.f / 256.f) - m * m;
  float rs = rsqrtf(var + 1e-5f);
  out[(size_t)n * HD + col] = (s - m) * rs * g_node[col] + b_node[col];
}

extern "C" void kernel_launch(void* const* d_in, const int* in_sizes, int n_in,
                              void* d_out, int out_size, void* d_ws, size_t ws_size,
                              hipStream_t stream)
{
  (void)in_sizes; (void)n_in; (void)out_size; (void)ws_size;
  const float* edge_features = (const float*)d_in[0];
  const int*   nmask  = (const int*)d_in[1];
  const float* W_lin  = (const float*)d_in[2];
  const float* b_lin  = (const float*)d_in[3];
  const float* g_pre  = (const float*)d_in[4];
  const float* b_pre  = (const float*)d_in[5];
  const float* W_ff1  = (const float*)d_in[6];
  const float* b_ff1  = (const float*)d_in[7];
  const float* W_ff2  = (const float*)d_in[8];
  const float* b_ff2  = (const float*)d_in[9];
  const float* g_node = (const float*)d_in[10];
  const float* b_node = (const float*)d_in[11];
  const float* g_edge = (const float*)d_in[12];
  const float* b_edge = (const float*)d_in[13];

  char* ws = (char*)d_ws;
  u16* eh    = (u16*)ws;   ws += (size_t)MROWS * HD * 2;   // edge_hidden bf16
  u16* gbuf  = (u16*)ws;   ws += (size_t)MROWS * HD * 2;   // gelu out, then eo (in-place)
  float* stats = (float*)ws; ws += (size_t)MROWS * 2 * 4;  // (m, rs) per row
  u16* Wlt   = (u16*)ws;   ws += 256 * 128 * 2;
  u16* W1gt  = (u16*)ws;   ws += 256 * 256 * 2;
  u16* W2t   = (u16*)ws;   ws += 256 * 256 * 2;
  float* uc  = (float*)ws; ws += 256 * 4;
  float* vc  = (float*)ws; ws += 256 * 4;

  float* node_out = (float*)d_out;
  float* edge_out = (float*)d_out + (size_t)NNODE * HD;

  prep_weights<<<640, 256, 0, stream>>>(W_lin, g_pre, W_ff1, W_ff2, Wlt, W1gt, W2t);
  prep_uv<<<1, 256, 0, stream>>>(W_ff1, g_pre, b_pre, b_ff1, uc, vc);
  gemm_k<128, 0><<<2500, 256, 0, stream>>>(edge_features, Wlt, b_lin, nullptr, nullptr,
                                           stats, eh, nullptr, nullptr);
  gemm_k<256, 1><<<2500, 256, 0, stream>>>(eh, W1gt, uc, vc, stats,
                                           nullptr, gbuf, nullptr, nullptr);
  gemm_k<256, 2><<<2500, 256, 0, stream>>>(gbuf, W2t, b_ff2, g_edge, b_edge,
                                           nullptr, gbuf, eh, edge_out);
  node_kernel<<<10000, 256, 0, stream>>>(gbuf, nmask, g_node, b_node, node_out);
}

// Round 2
// 701.475 us; speedup vs baseline: 1.3976x; 1.3976x over previous
//
#include <hip/hip_runtime.h>

typedef float f32x4 __attribute__((ext_vector_type(4)));
typedef float f32x2 __attribute__((ext_vector_type(2)));
typedef short bf16x8 __attribute__((ext_vector_type(8)));
typedef unsigned int u32;
typedef unsigned int u32x2 __attribute__((ext_vector_type(2)));
typedef unsigned short u16;

#define DEVI static __device__ __forceinline__

static constexpr int MROWS = 320000;   // N*K rows
static constexpr int HD    = 256;      // hidden
static constexpr int NNODE = 10000;

DEVI u16 f2bf(float f) {
  u32 u = __builtin_bit_cast(u32, f);
  u = (u + 0x7fffu + ((u >> 16) & 1u)) >> 16;   // RNE
  return (u16)u;
}
DEVI float bf2f(u16 s) {
  u32 u = ((u32)s) << 16;
  return __builtin_bit_cast(float, u);
}
DEVI float gelu_f(float y) {
  float z = 0.7978845608028654f * (y + 0.044715f * y * y * y);
  float E = __expf(2.f * z);
  return y * (1.f - 1.f / (E + 1.f));
}

// ---------------- weight prep ----------------
// Wlt [256][128] = W_lin^T (bf16); W1gt[256][256] = (g_pre*W_ff1)^T; W2t = W_ff2^T
__global__ void prep_weights(const float* __restrict__ W_lin, const float* __restrict__ g_pre,
                             const float* __restrict__ W_ff1, const float* __restrict__ W_ff2,
                             u16* __restrict__ Wlt, u16* __restrict__ W1gt, u16* __restrict__ W2t)
{
  int e = blockIdx.x * 256 + threadIdx.x;
  if (e < 32768) {
    int c = e >> 7, k = e & 127;
    Wlt[e] = f2bf(W_lin[k * 256 + c]);
  } else if (e < 32768 + 65536) {
    int e2 = e - 32768; int c = e2 >> 8, k = e2 & 255;
    W1gt[e2] = f2bf(g_pre[k] * W_ff1[k * 256 + c]);
  } else if (e < 163840) {
    int e3 = e - 98304; int c = e3 >> 8, k = e3 & 255;
    W2t[e3] = f2bf(W_ff2[k * 256 + c]);
  }
}

__global__ void prep_uv(const float* __restrict__ W_ff1, const float* __restrict__ g_pre,
                        const float* __restrict__ b_pre, const float* __restrict__ b_ff1,
                        float* __restrict__ u, float* __restrict__ v)
{
  int c = threadIdx.x;
  float uu = 0.f, vv = 0.f;
  for (int k = 0; k < 256; ++k) {
    float w = W_ff1[k * 256 + c];
    uu += g_pre[k] * w;
    vv += b_pre[k] * w;
  }
  u[c] = uu;
  v[c] = vv + b_ff1[c];
}

// ---------------- megakernel helpers ----------------
// Stage one [256 cols][32 k] bf16 chunk (16 KB) of a transposed weight matrix
// into LDS via global_load_lds, with slot-swizzle pre-applied on the SOURCE
// address (LDS dest stays linear: wave-uniform base + lane*16).
// LDS layout: col c occupies 64 B; slot s (16B) of col c holds k-chunk (s ^ ((c>>1)&3)).
DEVI void stage_w(const u16* __restrict__ Wt, int KD2, int c, char* buf, int wid, int lane) {
#pragma unroll
  for (int j2 = 0; j2 < 2; ++j2) {
    int j = wid * 2 + j2;                 // wave-chunk 0..15 (1 KB each)
    int L = j * 1024 + lane * 16;         // linear LDS offset this lane receives
    int cL = L >> 6;                      // col 0..255
    int kk = ((L >> 4) & 3) ^ ((cL >> 1) & 3);
    const char* g = (const char*)Wt + (size_t)cL * (size_t)KD2 + (size_t)c * 64 + (size_t)kk * 16;
    __builtin_amdgcn_global_load_lds((const __attribute__((address_space(1))) void*)g,
                                     (__attribute__((address_space(3))) void*)(buf + j * 1024),
                                     16, 0, 0);
  }
}

// One GEMM pass: acc[rg][nt] += A-tile (from swizzled LDS, STRIDE bytes/row) x W (staged chunks).
// Wave grid 2x4: wave rows [wr*64,+64), cols [wc*64,+64).
template<int NK, int STRIDE, bool SKIP0>
DEVI void run_gemm(f32x4 (&acc)[4][4], const char* xbase, const u16* __restrict__ Wt,
                   char* wstBase, int wid, int lane, int wr, int wc)
{
  const int lo = lane & 15, hi = lane >> 4;
  constexpr int KD2 = NK * 64;            // bytes per weight col row
  if (!SKIP0) stage_w(Wt, KD2, 0, wstBase, wid, lane);
  __syncthreads();
#pragma unroll
  for (int c = 0; c < NK; ++c) {
    if (c + 1 < NK) stage_w(Wt, KD2, c + 1, wstBase + ((c + 1) & 1) * 16384, wid, lane);
    bf16x8 a[4], b[4];
#pragma unroll
    for (int rg = 0; rg < 4; ++rg) {
      int r = wr * 64 + rg * 16 + lo;
      a[rg] = *(const bf16x8*)(xbase + r * STRIDE + ((((c * 4 + hi) ^ (r & 7))) << 4));
    }
    const char* wb = wstBase + (c & 1) * 16384;
#pragma unroll
    for (int nt = 0; nt < 4; ++nt) {
      int cc = wc * 64 + nt * 16 + lo;
      b[nt] = *(const bf16x8*)(wb + cc * 64 + ((hi ^ ((cc >> 1) & 3)) << 4));
    }
#pragma unroll
    for (int nt = 0; nt < 4; ++nt)
#pragma unroll
      for (int rg = 0; rg < 4; ++rg)
        acc[rg][nt] = __builtin_amdgcn_mfma_f32_16x16x32_bf16(b[nt], a[rg], acc[rg][nt], 0, 0, 0);
    __syncthreads();
  }
}

// ---------------- fused megakernel ----------------
// Block = 128 rows = 4 nodes. 512 threads = 8 waves (2 row-groups x 4 col-groups).
// xLDS [128][256] bf16 (swizzled) serves as: A-stage (first 32KB) -> eh -> g -> eo.
// Residual eh tile kept packed-bf16 in registers.
__global__ __launch_bounds__(512, 2)
void mega_kernel(const float* __restrict__ EF, const int* __restrict__ nmask,
                 const u16* __restrict__ Wlt, const u16* __restrict__ W1gt, const u16* __restrict__ W2t,
                 const float* __restrict__ b_lin, const float* __restrict__ uc, const float* __restrict__ vc,
                 const float* __restrict__ b_ff2, const float* __restrict__ g_edge, const float* __restrict__ b_edge,
                 const float* __restrict__ g_node, const float* __restrict__ b_node,
                 float* __restrict__ node_out, float* __restrict__ edge_out)
{
  const int tid  = threadIdx.x;
  const int wid  = tid >> 6;
  const int lane = tid & 63;
  const int lo   = lane & 15;
  const int hi   = lane >> 4;
  const int wr   = wid >> 2;      // 0..1
  const int wc   = wid & 3;       // 0..3
  const int tile0 = blockIdx.x * 128;

  __shared__ char  xLDS[65536];
  __shared__ char  wst[2][16384];
  __shared__ float part[4][128][2];
  __shared__ float red[8][2];

  // ---- issue first weight chunk, then stage A (fp32 -> bf16) into xLDS[0..32K) ----
  stage_w(Wlt, 256, 0, &wst[0][0], wid, lane);
#pragma unroll
  for (int it = 0; it < 4; ++it) {
    int ch = tid + it * 512;            // 2048 chunks: row r, slot sl (8 floats)
    int r = ch >> 4, sl = ch & 15;
    const float* src = EF + (size_t)(tile0 + r) * 128 + sl * 8;
    f32x4 x0 = *(const f32x4*)src;
    f32x4 x1 = *(const f32x4*)(src + 4);
    bf16x8 t;
    t[0] = (short)f2bf(x0[0]); t[1] = (short)f2bf(x0[1]);
    t[2] = (short)f2bf(x0[2]); t[3] = (short)f2bf(x0[3]);
    t[4] = (short)f2bf(x1[0]); t[5] = (short)f2bf(x1[1]);
    t[6] = (short)f2bf(x1[2]); t[7] = (short)f2bf(x1[3]);
    *(bf16x8*)(xLDS + r * 256 + ((sl ^ (r & 7)) << 4)) = t;
  }

  f32x4 acc[4][4];
#pragma unroll
  for (int rg = 0; rg < 4; ++rg)
#pragma unroll
    for (int nt = 0; nt < 4; ++nt) acc[rg][nt] = f32x4{0.f, 0.f, 0.f, 0.f};

  // ---- GEMM1: eh = EF x W_lin ----
  run_gemm<4, 256, true>(acc, xLDS, Wlt, &wst[0][0], wid, lane, wr, wc);

  // ---- EPI1: +b_lin, write eh (LDS + regs), row stats ----
  u32x2 ehreg[4][4];
  {
    f32x4 bl[4];
#pragma unroll
    for (int nt = 0; nt < 4; ++nt)
      bl[nt] = *(const f32x4*)(b_lin + wc * 64 + nt * 16 + hi * 4);
#pragma unroll
    for (int rg = 0; rg < 4; ++rg) {
      int r = wr * 64 + rg * 16 + lo;
      float ss = 0.f, qq = 0.f;
#pragma unroll
      for (int nt = 0; nt < 4; ++nt) {
        f32x4 x = acc[rg][nt] + bl[nt];
        u32 w0 = (u32)f2bf(x[0]) | ((u32)f2bf(x[1]) << 16);
        u32 w1 = (u32)f2bf(x[2]) | ((u32)f2bf(x[3]) << 16);
        ehreg[rg][nt] = u32x2{w0, w1};
        int slot = wc * 8 + nt * 2 + (hi >> 1);
        *(u32x2*)(xLDS + r * 512 + ((slot ^ (r & 7)) << 4) + (hi & 1) * 8) = ehreg[rg][nt];
        ss += x[0] + x[1] + x[2] + x[3];
        qq += x[0]*x[0] + x[1]*x[1] + x[2]*x[2] + x[3]*x[3];
      }
      ss += __shfl_xor(ss, 16); ss += __shfl_xor(ss, 32);
      qq += __shfl_xor(qq, 16); qq += __shfl_xor(qq, 32);
      if (hi == 0) { part[wc][r][0] = ss; part[wc][r][1] = qq; }
    }
  }
  __syncthreads();
  if (tid < 128) {
    float ss = part[0][tid][0] + part[1][tid][0] + part[2][tid][0] + part[3][tid][0];
    float qq = part[0][tid][1] + part[1][tid][1] + part[2][tid][1] + part[3][tid][1];
    float m  = ss * (1.f / 256.f);
    float var = qq * (1.f / 256.f) - m * m;
    part[0][tid][0] = m;
    part[0][tid][1] = rsqrtf(var + 1e-5f);
  }
  __syncthreads();
  float rsr[4], rmr[4];
#pragma unroll
  for (int rg = 0; rg < 4; ++rg) {
    int r = wr * 64 + rg * 16 + lo;
    float m = part[0][r][0], rs = part[0][r][1];
    rsr[rg] = rs; rmr[rg] = m * rs;
  }

  // ---- GEMM2: acc = eh x (g_pre*W_ff1) ----
#pragma unroll
  for (int rg = 0; rg < 4; ++rg)
#pragma unroll
    for (int nt = 0; nt < 4; ++nt) acc[rg][nt] = f32x4{0.f, 0.f, 0.f, 0.f};
  run_gemm<8, 512, false>(acc, xLDS, W1gt, &wst[0][0], wid, lane, wr, wc);

  // ---- EPI2: folded pre-LN + gelu -> g into xLDS ----
  {
    f32x4 u4[4], v4[4];
#pragma unroll
    for (int nt = 0; nt < 4; ++nt) {
      u4[nt] = *(const f32x4*)(uc + wc * 64 + nt * 16 + hi * 4);
      v4[nt] = *(const f32x4*)(vc + wc * 64 + nt * 16 + hi * 4);
    }
#pragma unroll
    for (int rg = 0; rg < 4; ++rg) {
      int r = wr * 64 + rg * 16 + lo;
#pragma unroll
      for (int nt = 0; nt < 4; ++nt) {
        f32x4 y = acc[rg][nt] * rsr[rg] - u4[nt] * rmr[rg] + v4[nt];
        u32 w0 = (u32)f2bf(gelu_f(y[0])) | ((u32)f2bf(gelu_f(y[1])) << 16);
        u32 w1 = (u32)f2bf(gelu_f(y[2])) | ((u32)f2bf(gelu_f(y[3])) << 16);
        int slot = wc * 8 + nt * 2 + (hi >> 1);
        *(u32x2*)(xLDS + r * 512 + ((slot ^ (r & 7)) << 4) + (hi & 1) * 8) = u32x2{w0, w1};
      }
    }
  }

  // ---- GEMM3: acc = g x W_ff2 ----
#pragma unroll
  for (int rg = 0; rg < 4; ++rg)
#pragma unroll
    for (int nt = 0; nt < 4; ++nt) acc[rg][nt] = f32x4{0.f, 0.f, 0.f, 0.f};
  run_gemm<8, 512, false>(acc, xLDS, W2t, &wst[0][0], wid, lane, wr, wc);

  // ---- EPI3: +b_ff2 + residual; edge LN stats ----
  f32x4 eo[4][4];
  f32x4 ge4[4], be4[4];
  {
    f32x4 b2[4];
#pragma unroll
    for (int nt = 0; nt < 4; ++nt) {
      b2[nt]  = *(const f32x4*)(b_ff2  + wc * 64 + nt * 16 + hi * 4);
      ge4[nt] = *(const f32x4*)(g_edge + wc * 64 + nt * 16 + hi * 4);
      be4[nt] = *(const f32x4*)(b_edge + wc * 64 + nt * 16 + hi * 4);
    }
#pragma unroll
    for (int rg = 0; rg < 4; ++rg) {
      int r = wr * 64 + rg * 16 + lo;
      float ss = 0.f, qq = 0.f;
#pragma unroll
      for (int nt = 0; nt < 4; ++nt) {
        f32x4 x = acc[rg][nt] + b2[nt];
        x[0] += bf2f((u16)(ehreg[rg][nt][0] & 0xffffu));
        x[1] += bf2f((u16)(ehreg[rg][nt][0] >> 16));
        x[2] += bf2f((u16)(ehreg[rg][nt][1] & 0xffffu));
        x[3] += bf2f((u16)(ehreg[rg][nt][1] >> 16));
        eo[rg][nt] = x;
        ss += x[0] + x[1] + x[2] + x[3];
        qq += x[0]*x[0] + x[1]*x[1] + x[2]*x[2] + x[3]*x[3];
      }
      ss += __shfl_xor(ss, 16); ss += __shfl_xor(ss, 32);
      qq += __shfl_xor(qq, 16); qq += __shfl_xor(qq, 32);
      if (hi == 0) { part[wc][r][0] = ss; part[wc][r][1] = qq; }
    }
  }
  __syncthreads();
  if (tid < 128) {
    float ss = part[0][tid][0] + part[1][tid][0] + part[2][tid][0] + part[3][tid][0];
    float qq = part[0][tid][1] + part[1][tid][1] + part[2][tid][1] + part[3][tid][1];
    float m  = ss * (1.f / 256.f);
    float var = qq * (1.f / 256.f) - m * m;
    part[0][tid][0] = m;
    part[0][tid][1] = rsqrtf(var + 1e-5f);
  }
  __syncthreads();
  // ---- edge_out (LN) global store + eo bf16 -> xLDS ----
#pragma unroll
  for (int rg = 0; rg < 4; ++rg) {
    int r = wr * 64 + rg * 16 + lo;
    float m2 = part[0][r][0], rs2 = part[0][r][1];
#pragma unroll
    for (int nt = 0; nt < 4; ++nt) {
      f32x4 x = eo[rg][nt];
      u32 w0 = (u32)f2bf(x[0]) | ((u32)f2bf(x[1]) << 16);
      u32 w1 = (u32)f2bf(x[2]) | ((u32)f2bf(x[3]) << 16);
      int slot = wc * 8 + nt * 2 + (hi >> 1);
      *(u32x2*)(xLDS + r * 512 + ((slot ^ (r & 7)) << 4) + (hi & 1) * 8) = u32x2{w0, w1};
      f32x4 o = (x - m2) * rs2 * ge4[nt] + be4[nt];
      *(f32x4*)(edge_out + (size_t)(tile0 + r) * 256 + wc * 64 + nt * 16 + hi * 4) = o;
    }
  }
  __syncthreads();

  // ---- node partial sums (masked) into np (aliases wstage) ----
  float* np = (float*)&wst[0][0];     // 16 KB: [4 node][32 cc][4 rq][8] (j xor-swizzled by cc&7)
  {
    int nd = tid >> 7, rest = tid & 127, cc = rest >> 2, rq = rest & 3;
    float p[8] = {0.f,0.f,0.f,0.f,0.f,0.f,0.f,0.f};
#pragma unroll
    for (int j = 0; j < 8; ++j) {
      int r = nd * 32 + rq * 8 + j;
      if (nmask[tile0 + r] != 0) {
        bf16x8 v = *(const bf16x8*)(xLDS + r * 512 + ((cc ^ (r & 7)) << 4));
#pragma unroll
        for (int k = 0; k < 8; ++k) p[k] += bf2f((u16)v[k]);
      }
    }
    int base = ((nd * 32 + cc) * 4 + rq) * 8;
    int sx = cc & 7;
#pragma unroll
    for (int j = 0; j < 8; ++j) np[base + (j ^ sx)] = p[j];
  }
  __syncthreads();

  // ---- node finalize: sum partials, node LN, store ----
  {
    int nd = tid >> 7, cp = tid & 127;
    int c0 = cp * 2;
    int cc = c0 >> 3, j0 = c0 & 7, sx = cc & 7;
    float s0 = 0.f, s1 = 0.f;
#pragma unroll
    for (int rq = 0; rq < 4; ++rq) {
      int base = ((nd * 32 + cc) * 4 + rq) * 8;
      s0 += np[base + (j0 ^ sx)];
      s1 += np[base + ((j0 + 1) ^ sx)];
    }
    float ss = s0 + s1, qq = s0 * s0 + s1 * s1;
#pragma unroll
    for (int d = 1; d < 64; d <<= 1) { ss += __shfl_xor(ss, d); qq += __shfl_xor(qq, d); }
    if (lane == 0) { red[wid][0] = ss; red[wid][1] = qq; }
    __syncthreads();
    ss = red[nd * 2][0] + red[nd * 2 + 1][0];
    qq = red[nd * 2][1] + red[nd * 2 + 1][1];
    float m  = ss * (1.f / 256.f);
    float var = qq * (1.f / 256.f) - m * m;
    float rs = rsqrtf(var + 1e-5f);
    f32x2 o;
    o[0] = (s0 - m) * rs * g_node[c0]     + b_node[c0];
    o[1] = (s1 - m) * rs * g_node[c0 + 1] + b_node[c0 + 1];
    *(f32x2*)(node_out + (size_t)(blockIdx.x * 4 + nd) * 256 + c0) = o;
  }
}

extern "C" void kernel_launch(void* const* d_in, const int* in_sizes, int n_in,
                              void* d_out, int out_size, void* d_ws, size_t ws_size,
                              hipStream_t stream)
{
  (void)in_sizes; (void)n_in; (void)out_size; (void)ws_size;
  const float* edge_features = (const float*)d_in[0];
  const int*   nmask  = (const int*)d_in[1];
  const float* W_lin  = (const float*)d_in[2];
  const float* b_lin  = (const float*)d_in[3];
  const float* g_pre  = (const float*)d_in[4];
  const float* b_pre  = (const float*)d_in[5];
  const float* W_ff1  = (const float*)d_in[6];
  const float* b_ff1  = (const float*)d_in[7];
  const float* W_ff2  = (const float*)d_in[8];
  const float* b_ff2  = (const float*)d_in[9];
  const float* g_node = (const float*)d_in[10];
  const float* b_node = (const float*)d_in[11];
  const float* g_edge = (const float*)d_in[12];
  const float* b_edge = (const float*)d_in[13];

  char* ws = (char*)d_ws;
  u16* Wlt   = (u16*)ws;   ws += 256 * 128 * 2;
  u16* W1gt  = (u16*)ws;   ws += 256 * 256 * 2;
  u16* W2t   = (u16*)ws;   ws += 256 * 256 * 2;
  float* uc  = (float*)ws; ws += 256 * 4;
  float* vc  = (float*)ws; ws += 256 * 4;

  float* node_out = (float*)d_out;
  float* edge_out = (float*)d_out + (size_t)NNODE * HD;

  prep_weights<<<640, 256, 0, stream>>>(W_lin, g_pre, W_ff1, W_ff2, Wlt, W1gt, W2t);
  prep_uv<<<1, 256, 0, stream>>>(W_ff1, g_pre, b_pre, b_ff1, uc, vc);
  mega_kernel<<<2500, 512, 0, stream>>>(edge_features, nmask, Wlt, W1gt, W2t,
                                        b_lin, uc, vc, b_ff2, g_edge, b_edge,
                                        g_node, b_node, node_out, edge_out);
}